// Round 8
// baseline (180.121 us; speedup 1.0000x reference)
//
#include <hip/hip_runtime.h>
#include <hip/hip_bf16.h>

#define NSLOT 8
#define SDIM 256
#define FDIM 128
#define NHEAD 4
#define HDIM 64
#define NPOS 4096

typedef short v8s __attribute__((ext_vector_type(8)));
typedef short v4s __attribute__((ext_vector_type(4)));
typedef float v4f __attribute__((ext_vector_type(4)));

__device__ __forceinline__ unsigned short f2bf(float x) {
    __hip_bfloat16 h = __float2bfloat16(x);
    unsigned short u; __builtin_memcpy(&u, &h, 2); return u;
}
__device__ __forceinline__ float bfr2f(unsigned short u) {
    __hip_bfloat16 h; __builtin_memcpy(&h, &u, 2); return __bfloat162float(h);
}
__device__ __forceinline__ void splitf(float x, unsigned short& hi, unsigned short& lo) {
    hi = f2bf(x);
    lo = f2bf(x - bfr2f(hi));
}

// ---------------- K1 (fused prep, 592 blocks):
//   blk   0..255: per-(batch,slot) LN+q+qkT/qb (b = blk>>3, s = blk&7)
//   blk 256..511: W1 / W2 transpose -> hi/lo bf16 [n][k]
//   blk 512..559: W_ih / W_hh (768x256 each) elementwise split -> hi/lo bf16
//   blk 560..591: Wv (128x256) transpose -> WvT hi/lo bf16 [256][128]
__global__ __launch_bounds__(256) void k_prep(
    const float* __restrict__ slots,
    const float* __restrict__ Wq, const float* __restrict__ bq,
    const float* __restrict__ g_pre, const float* __restrict__ b_pre,
    const float* __restrict__ Wk, const float* __restrict__ bk,
    const float* __restrict__ W1, const float* __restrict__ W2,
    const float* __restrict__ W_ih, const float* __restrict__ W_hh,
    const float* __restrict__ Wv,
    unsigned short* __restrict__ qkT_ws, float* __restrict__ qb_ws,
    unsigned short* __restrict__ W1Th, unsigned short* __restrict__ W1Tl,
    unsigned short* __restrict__ W2Th, unsigned short* __restrict__ W2Tl,
    unsigned short* __restrict__ WihH, unsigned short* __restrict__ WihL,
    unsigned short* __restrict__ WhhH, unsigned short* __restrict__ WhhL,
    unsigned short* __restrict__ WvTH, unsigned short* __restrict__ WvTl,
    float* __restrict__ agg_ws)
{
    int blk = blockIdx.x, t = threadIdx.x;
    __shared__ __align__(16) float s_ln[256];
    __shared__ __align__(16) float q_l[256];
    __shared__ float r1[4], r2[4];
    __shared__ float tl[32][33];

    if (blk >= 560) {                // WvT transpose+split (32 blocks)
        int id3 = blk - 560;
        int k0 = (id3 & 3) * 32, n0 = (id3 >> 2) * 32;
        for (int i = 0; i < 4; i++) {
            int idx = i * 256 + t, r = idx >> 5, c = idx & 31;
            tl[r][c] = Wv[(size_t)(k0 + r) * 256 + n0 + c];
        }
        __syncthreads();
        for (int i = 0; i < 4; i++) {
            int idx = i * 256 + t, r = idx >> 5, c = idx & 31;
            unsigned short hi, lo; splitf(tl[c][r], hi, lo);
            WvTH[(size_t)(n0 + r) * 128 + k0 + c] = hi;
            WvTl[(size_t)(n0 + r) * 128 + k0 + c] = lo;
        }
        return;
    }
    if (blk >= 512) {                // gate-weight split: 768 rows each (24 blocks each)
        int id2 = blk - 512;         // 0..47
        const float* src; unsigned short *dh, *dl; int r0;
        if (id2 < 24) { src = W_ih; dh = WihH; dl = WihL; r0 = id2 * 32; }
        else          { src = W_hh; dh = WhhH; dl = WhhL; r0 = (id2 - 24) * 32; }
        for (int i = 0; i < 32; i++) {
            size_t idx = (size_t)(r0 + i) * 256 + t;
            unsigned short hi, lo; splitf(src[idx], hi, lo);
            dh[idx] = hi; dl[idx] = lo;
        }
        return;
    }
    if (blk >= 256) {                // W1/W2 transpose+split
        int id = blk - 256;          // 0..255
        const float* src; unsigned short *dh, *dl; int N, K, k0, n0;
        if (id < 128) { src = W1; dh = W1Th; dl = W1Tl; N = 512; K = 256;
                        k0 = (id >> 4) * 32; n0 = (id & 15) * 32; }
        else          { int i2 = id - 128; src = W2; dh = W2Th; dl = W2Tl; N = 256; K = 512;
                        k0 = (i2 >> 3) * 32; n0 = (i2 & 7) * 32; }
        for (int i = 0; i < 4; i++) {
            int idx = i * 256 + t, r = idx >> 5, c = idx & 31;
            tl[r][c] = src[(size_t)(k0 + r) * N + n0 + c];
        }
        __syncthreads();
        for (int i = 0; i < 4; i++) {
            int idx = i * 256 + t, r = idx >> 5, c = idx & 31;
            unsigned short hi, lo; splitf(tl[c][r], hi, lo);
            dh[(size_t)(n0 + r) * K + k0 + c] = hi;
            dl[(size_t)(n0 + r) * K + k0 + c] = lo;
        }
        return;
    }

    // ---- per-(batch,slot) prep: b = blk>>3, s = blk&7 ----
    int b = blk >> 3, s = blk & 7;
    if (s == 0)
        for (int i = 0; i < 8; i++) agg_ws[b * 2048 + i * 256 + t] = 0.0f;

    // LN of slot row (b,s): one element per thread
    float x = slots[(size_t)(b * 8 + s) * 256 + t];
    float sum = x, sq = x * x;
    #pragma unroll
    for (int m = 1; m <= 32; m <<= 1) {
        sum += __shfl_xor(sum, m, 64);
        sq  += __shfl_xor(sq, m, 64);
    }
    int w = t >> 6, lane = t & 63;
    if (lane == 0) { r1[w] = sum; r2[w] = sq; }
    __syncthreads();
    sum = r1[0] + r1[1] + r1[2] + r1[3];
    sq  = r2[0] + r2[1] + r2[2] + r2[3];
    float mu  = sum * (1.0f / 256);
    float var = sq * (1.0f / 256) - mu * mu;
    float rstd = rsqrtf(var + 1e-5f);
    s_ln[t] = (x - mu) * rstd * g_pre[t] + b_pre[t];
    __syncthreads();

    // q column t for this slot: q[t] = bq[t] + sum_k ln[k]*Wq[k][t]
    float qacc = bq[t];
    for (int k = 0; k < 256; k += 4) {
        float4 l4 = *(const float4*)&s_ln[k];       // uniform -> LDS broadcast
        qacc += l4.x * Wq[(k + 0) * 256 + t]
              + l4.y * Wq[(k + 1) * 256 + t]
              + l4.z * Wq[(k + 2) * 256 + t]
              + l4.w * Wq[(k + 3) * 256 + t];
    }
    q_l[t] = qacc;
    __syncthreads();

    // qkT rows (h*8+s) for this slot: thread (c = t&127) does heads h0, h0+2
    int c = t & 127, h0 = t >> 7;
    #pragma unroll
    for (int hi_ = 0; hi_ < 2; hi_++) {
        int hh = h0 + hi_ * 2;
        const float4* wk4 = (const float4*)&Wk[(size_t)c * 256 + hh * 64];
        const float4* q4  = (const float4*)&q_l[hh * 64];
        float acc = 0.0f;
        #pragma unroll
        for (int d4 = 0; d4 < 16; d4++) {
            float4 wv = wk4[d4]; float4 qv = q4[d4];
            acc += wv.x * qv.x + wv.y * qv.y + wv.z * qv.z + wv.w * qv.w;
        }
        qkT_ws[(size_t)(b * 32 + hh * 8 + s) * 128 + c] = f2bf(acc);
    }
    if (t < 4) {
        float acc = 0.0f;
        for (int d = 0; d < 64; d++)
            acc += bk[t * 64 + d] * q_l[t * 64 + d];
        qb_ws[b * 32 + t * 8 + s] = acc;
    }
}

// ---------------- K2: MFMA scores + in-register softmax + MFMA attF^T + epi.
// Grid (16,32): each block covers 256 positions (8 tt-tiles of 32). Doubles
// the contiguous HBM run per channel row (512B -> 1KB), halves epilogue
// MFMA work + atomics + block count, keeps 512 blocks = 2/CU, 8 waves/CU.
__global__ __launch_bounds__(256, 4) void k_attn(
    const float* __restrict__ feat,   // (B,128,4096)
    const unsigned short* __restrict__ WvTH, const unsigned short* __restrict__ WvTl,
    const float* __restrict__ bv,
    const unsigned short* __restrict__ qkT, const float* __restrict__ qb_ws,
    float* __restrict__ agg_ws)
{
    __shared__ __align__(16) char smem[26752];
    unsigned short* featPC = (unsigned short*)smem;              // stride 136
    unsigned short* featCP = (unsigned short*)(smem + 8704);     // stride 56
    unsigned short* attFH  = (unsigned short*)smem;              // alias, stride 136
    unsigned short* attFL  = (unsigned short*)(smem + 8704);     // alias, stride 136
    unsigned short* s_aT   = (unsigned short*)(smem + 23040);    // stride 56
    float*          s_S    = (float*)(smem + 26624);

    int t = threadIdx.x, b = blockIdx.y, n0 = blockIdx.x * 256;
    int wv_ = t >> 6, lane = t & 63, quad = lane >> 4, l16 = lane & 15;
    int mt = wv_ >> 1, nt = wv_ & 1;
    int sp  = l16 + mt * 16;
    int shs = l16 + nt * 16;

    v8s bq_[4];
    #pragma unroll
    for (int ch = 0; ch < 4; ch++)
        bq_[ch] = *(const v8s*)&qkT[(b * 32 + shs) * 128 + ch * 32 + quad * 8];
    float qbv = qb_ws[b * 32 + shs];
    if (t < 32) s_S[t] = 0.0f;

    v4f accF[4];
    #pragma unroll
    for (int i = 0; i < 4; i++) accF[i] = (v4f){0.f, 0.f, 0.f, 0.f};
    float sS_reg = 0.0f;

    int c0 = (t >> 3) * 4, p0 = (t & 7) * 4;
    size_t fbase = (size_t)b * (FDIM * NPOS);

    // prefetch tile 0
    float fv[4][4];
    #pragma unroll
    for (int r = 0; r < 4; r++) {
        float4 f = *(const float4*)&feat[fbase + (size_t)(c0 + r) * NPOS + n0 + p0];
        fv[r][0] = f.x; fv[r][1] = f.y; fv[r][2] = f.z; fv[r][3] = f.w;
    }

    #pragma unroll
    for (int tt = 0; tt < 8; ++tt) {
        __syncthreads();
        // stage: convert ONCE, write both layouts
        unsigned short us[4][4];
        #pragma unroll
        for (int r = 0; r < 4; r++)
            #pragma unroll
            for (int j = 0; j < 4; j++) us[r][j] = f2bf(fv[r][j]);
        #pragma unroll
        for (int r = 0; r < 4; r++)
            *(v4s*)&featCP[(c0 + r) * 56 + p0] =
                (v4s){(short)us[r][0], (short)us[r][1], (short)us[r][2], (short)us[r][3]};
        #pragma unroll
        for (int j = 0; j < 4; j++)
            *(v4s*)&featPC[(p0 + j) * 136 + c0] =
                (v4s){(short)us[0][j], (short)us[1][j], (short)us[2][j], (short)us[3][j]};
        __syncthreads();

        // prefetch next tile under the compute below (T14)
        if (tt < 7) {
            #pragma unroll
            for (int r = 0; r < 4; r++) {
                float4 f = *(const float4*)&feat[fbase + (size_t)(c0 + r) * NPOS
                                                 + n0 + (tt + 1) * 32 + p0];
                fv[r][0] = f.x; fv[r][1] = f.y; fv[r][2] = f.z; fv[r][3] = f.w;
            }
        }

        v4f acc = (v4f){0.f, 0.f, 0.f, 0.f};
        #pragma unroll
        for (int ch = 0; ch < 4; ch++) {
            v8s a = *(const v8s*)&featPC[sp * 136 + ch * 32 + quad * 8];
            acc = __builtin_amdgcn_mfma_f32_16x16x32_bf16(a, bq_[ch], acc, 0, 0, 0);
        }

        // ---- in-register softmax over the 8-lane slot group ----
        float p[4];
        {
            float sc[4], e[4];
            #pragma unroll
            for (int r = 0; r < 4; r++) sc[r] = (acc[r] + qbv) * 0.125f;
            #pragma unroll
            for (int r = 0; r < 4; r++) {
                float m = sc[r];
                m = fmaxf(m, __shfl_xor(m, 1, 64));
                m = fmaxf(m, __shfl_xor(m, 2, 64));
                m = fmaxf(m, __shfl_xor(m, 4, 64));
                e[r] = __expf(sc[r] - m);
            }
            #pragma unroll
            for (int r = 0; r < 4; r++) {
                float ssum = e[r];
                ssum += __shfl_xor(ssum, 1, 64);
                ssum += __shfl_xor(ssum, 2, 64);
                ssum += __shfl_xor(ssum, 4, 64);
                p[r] = e[r] * (1.0f / ssum);
            }
        }
        // write P in [col][pos] layout for the PV MFMA A-operand
        *(v4s*)&s_aT[shs * 56 + mt * 16 + quad * 4] =
            (v4s){(short)f2bf(p[0]), (short)f2bf(p[1]),
                  (short)f2bf(p[2]), (short)f2bf(p[3])};
        // accumulate column sum (this wave's 16 positions) in a register
        {
            float sl = p[0] + p[1] + p[2] + p[3];
            sl += __shfl_xor(sl, 16, 64);
            sl += __shfl_xor(sl, 32, 64);
            sS_reg += sl;
        }
        __syncthreads();

        v8s aA0 = *(const v8s*)&s_aT[l16 * 56 + quad * 8];
        v8s aA1 = *(const v8s*)&s_aT[(l16 + 16) * 56 + quad * 8];
        v8s bF0 = *(const v8s*)&featCP[(l16 + wv_ * 32) * 56 + quad * 8];
        v8s bF1 = *(const v8s*)&featCP[(l16 + wv_ * 32 + 16) * 56 + quad * 8];
        accF[0] = __builtin_amdgcn_mfma_f32_16x16x32_bf16(aA0, bF0, accF[0], 0, 0, 0);
        accF[1] = __builtin_amdgcn_mfma_f32_16x16x32_bf16(aA0, bF1, accF[1], 0, 0, 0);
        accF[2] = __builtin_amdgcn_mfma_f32_16x16x32_bf16(aA1, bF0, accF[2], 0, 0, 0);
        accF[3] = __builtin_amdgcn_mfma_f32_16x16x32_bf16(aA1, bF1, accF[3], 0, 0, 0);
    }
    // flush the per-wave column sums
    if (quad == 0) atomicAdd(&s_S[shs], sS_reg);
    __syncthreads();                 // feats views dead; alias as attFH/attFL
    #pragma unroll
    for (int mt2 = 0; mt2 < 2; mt2++)
        #pragma unroll
        for (int ntl = 0; ntl < 2; ntl++) {
            v4f f = accF[mt2 * 2 + ntl];
            int cc = wv_ * 32 + ntl * 16 + l16;
            #pragma unroll
            for (int r = 0; r < 4; r++) {
                unsigned short hi, lo; splitf(f[r], hi, lo);
                attFH[(mt2 * 16 + quad * 4 + r) * 136 + cc] = hi;
                attFL[(mt2 * 16 + quad * 4 + r) * 136 + cc] = lo;
            }
        }
    __syncthreads();

    int h = wv_;
    int am = h * 8 + (l16 & 7);
    for (int nt2 = 0; nt2 < 4; nt2++) {
        int n = h * 64 + nt2 * 16 + l16;
        v4f acc = (v4f){0.f, 0.f, 0.f, 0.f};
        #pragma unroll
        for (int kk = 0; kk < 4; kk++) {
            int ko = kk * 32 + quad * 8;
            v8s ah = *(const v8s*)&attFH[am * 136 + ko];
            v8s al = *(const v8s*)&attFL[am * 136 + ko];
            v8s bh = *(const v8s*)&WvTH[(size_t)n * 128 + ko];
            v8s bl = *(const v8s*)&WvTl[(size_t)n * 128 + ko];
            acc = __builtin_amdgcn_mfma_f32_16x16x32_bf16(al, bh, acc, 0, 0, 0);
            acc = __builtin_amdgcn_mfma_f32_16x16x32_bf16(ah, bl, acc, 0, 0, 0);
            acc = __builtin_amdgcn_mfma_f32_16x16x32_bf16(ah, bh, acc, 0, 0, 0);
        }
        float bvn = bv[n];
        if (quad < 2) {
            #pragma unroll
            for (int r = 0; r < 4; r++) {
                int s = quad * 4 + r;
                atomicAdd(&agg_ws[b * 2048 + s * 256 + n],
                          acc[r] + s_S[h * 8 + s] * bvn);
            }
        }
    }
}

// ---------------- K3: G[256][1536] = [x@W_ih^T + b_ih | h@W_hh^T + b_hh] ---
// 384 blocks (24 ntiles x 16 mtiles), 4 waves, ONE 16x16 tile per wave.
__global__ __launch_bounds__(256) void k_gate(
    const float* __restrict__ agg, const float* __restrict__ slots,
    const unsigned short* __restrict__ WihH, const unsigned short* __restrict__ WihL,
    const float* __restrict__ b_ih,
    const unsigned short* __restrict__ WhhH, const unsigned short* __restrict__ WhhL,
    const float* __restrict__ b_hh,
    float* __restrict__ G)
{
    int ntile = blockIdx.x, mtile = blockIdx.y, t = threadIdx.x;
    bool hhalf = ntile >= 12;
    int jbase = (hhalf ? ntile - 12 : ntile) * 64;
    const float* X = hhalf ? slots : agg;
    const unsigned short* BH = hhalf ? WhhH : WihH;
    const unsigned short* BL = hhalf ? WhhL : WihL;
    const float* bias = hhalf ? b_hh : b_ih;
    int gofs = hhalf ? 768 : 0;
    int m0 = mtile * 16;

    __shared__ __align__(16) unsigned short aH[16][264];
    __shared__ __align__(16) unsigned short aL[16][264];
    for (int i = 0; i < 4; i++) {
        int idx = i * 256 + t;           // 0..1023
        int r = idx >> 6, q = idx & 63;
        float4 f = *(const float4*)&X[(size_t)(m0 + r) * 256 + q * 4];
        unsigned short h0,l0,h1,l1,h2,l2,h3,l3;
        splitf(f.x, h0, l0); splitf(f.y, h1, l1);
        splitf(f.z, h2, l2); splitf(f.w, h3, l3);
        *(v4s*)&aH[r][q * 4] = (v4s){(short)h0,(short)h1,(short)h2,(short)h3};
        *(v4s*)&aL[r][q * 4] = (v4s){(short)l0,(short)l1,(short)l2,(short)l3};
    }
    __syncthreads();

    int w = t >> 6, lane = t & 63, quad = lane >> 4, l16 = lane & 15;
    int jrow = jbase + w * 16 + l16;     // 0..767
    v4f acc = (v4f){0.f, 0.f, 0.f, 0.f};
    #pragma unroll
    for (int kk = 0; kk < 8; kk++) {
        int ko = kk * 32 + quad * 8;
        v8s ah = *(const v8s*)&aH[l16][ko];
        v8s al = *(const v8s*)&aL[l16][ko];
        v8s bh = *(const v8s*)&BH[(size_t)jrow * 256 + ko];
        v8s bl = *(const v8s*)&BL[(size_t)jrow * 256 + ko];
        acc = __builtin_amdgcn_mfma_f32_16x16x32_bf16(al, bh, acc, 0, 0, 0);
        acc = __builtin_amdgcn_mfma_f32_16x16x32_bf16(ah, bl, acc, 0, 0, 0);
        acc = __builtin_amdgcn_mfma_f32_16x16x32_bf16(ah, bh, acc, 0, 0, 0);
    }
    float bv_ = bias[jrow];
    int gj = gofs + jbase + w * 16 + l16;
    #pragma unroll
    for (int r = 0; r < 4; r++)
        G[(size_t)(m0 + quad * 4 + r) * 1536 + gj] = acc[r] + bv_;
}

__device__ __forceinline__ float gru1(float ir, float iz, float in_,
                                      float hr, float hz, float hn, float hp) {
    float r = 1.0f / (1.0f + __expf(-(ir + hr)));
    float z = 1.0f / (1.0f + __expf(-(iz + hz)));
    float n = tanhf(in_ + r * hn);
    return (1.0f - z) * n + z * hp;
}

// ---------------- K4: GRU + post-LN, 64 blocks x 256 thr, 4 rows/block.
__global__ __launch_bounds__(256) void k_gru(
    const float* __restrict__ slots, const float* __restrict__ G,
    const float* __restrict__ g_post, const float* __restrict__ b_post,
    unsigned short* __restrict__ lnH_g, unsigned short* __restrict__ lnL_g,
    float* __restrict__ hnF)
{
    __shared__ float pS[4][4], pQ[4][4];
    int t = threadIdx.x, m0 = blockIdx.x * 4;
    int w = t >> 6, lane = t & 63;

    float hnew[4];
    #pragma unroll
    for (int r = 0; r < 4; r++) {
        int row = m0 + r;
        const float* gp = &G[(size_t)row * 1536 + t];
        float hp = slots[(size_t)row * 256 + t];
        hnew[r] = gru1(gp[0], gp[256], gp[512], gp[768], gp[1024], gp[1280], hp);
        hnF[(size_t)row * 256 + t] = hnew[r];
    }
    float ps[4], pq[4];
    #pragma unroll
    for (int r = 0; r < 4; r++) { ps[r] = hnew[r]; pq[r] = hnew[r] * hnew[r]; }
    #pragma unroll
    for (int mm = 1; mm <= 32; mm <<= 1)
        #pragma unroll
        for (int r = 0; r < 4; r++) {
            ps[r] += __shfl_xor(ps[r], mm, 64);
            pq[r] += __shfl_xor(pq[r], mm, 64);
        }
    if (lane == 0)
        #pragma unroll
        for (int r = 0; r < 4; r++) { pS[r][w] = ps[r]; pQ[r][w] = pq[r]; }
    __syncthreads();
    float gpv = g_post[t], bpv = b_post[t];
    #pragma unroll
    for (int r = 0; r < 4; r++) {
        float s = pS[r][0] + pS[r][1] + pS[r][2] + pS[r][3];
        float q = pQ[r][0] + pQ[r][1] + pQ[r][2] + pQ[r][3];
        float mu = s * (1.0f / 256);
        float var = q * (1.0f / 256) - mu * mu;
        float rstd = rsqrtf(var + 1e-5f);
        float ln = (hnew[r] - mu) * rstd * gpv + bpv;
        unsigned short hi, lo; splitf(ln, hi, lo);
        lnH_g[(size_t)(m0 + r) * 256 + t] = hi;
        lnL_g[(size_t)(m0 + r) * 256 + t] = lo;
    }
}

// ---------------- K5: MLP1 y1 = relu(ln@W1+b1) — grid (8,16) = 128 blocks,
// 4 waves, 1 16x16 tile/wave.
__global__ __launch_bounds__(256) void k_mlp1(
    const unsigned short* __restrict__ lnH_g, const unsigned short* __restrict__ lnL_g,
    const unsigned short* __restrict__ W1Th, const unsigned short* __restrict__ W1Tl,
    const float* __restrict__ b1,
    unsigned short* __restrict__ y1H_g, unsigned short* __restrict__ y1L_g)
{
    int ncl = blockIdx.x, mtile = blockIdx.y, t = threadIdx.x;
    int m0 = mtile * 16;
    __shared__ __align__(16) unsigned short aH[16][264];
    __shared__ __align__(16) unsigned short aL[16][264];
    {
        int r = t >> 4, c0 = (t & 15) * 16;
        *(v8s*)&aH[r][c0]     = *(const v8s*)&lnH_g[(size_t)(m0 + r) * 256 + c0];
        *(v8s*)&aH[r][c0 + 8] = *(const v8s*)&lnH_g[(size_t)(m0 + r) * 256 + c0 + 8];
        *(v8s*)&aL[r][c0]     = *(const v8s*)&lnL_g[(size_t)(m0 + r) * 256 + c0];
        *(v8s*)&aL[r][c0 + 8] = *(const v8s*)&lnL_g[(size_t)(m0 + r) * 256 + c0 + 8];
    }
    __syncthreads();

    int w = t >> 6, lane = t & 63, quad = lane >> 4, l16 = lane & 15;
    int n = (ncl * 4 + w) * 16 + l16;       // 0..511
    v4f acc = (v4f){0.f, 0.f, 0.f, 0.f};
    #pragma unroll
    for (int kk = 0; kk < 8; kk++) {
        int ko = kk * 32 + quad * 8;
        v8s ah = *(const v8s*)&aH[l16][ko];
        v8s al = *(const v8s*)&aL[l16][ko];
        v8s bh = *(const v8s*)&W1Th[(size_t)n * 256 + ko];
        v8s bl = *(const v8s*)&W1Tl[(size_t)n * 256 + ko];
        acc = __builtin_amdgcn_mfma_f32_16x16x32_bf16(al, bh, acc, 0, 0, 0);
        acc = __builtin_amdgcn_mfma_f32_16x16x32_bf16(ah, bl, acc, 0, 0, 0);
        acc = __builtin_amdgcn_mfma_f32_16x16x32_bf16(ah, bh, acc, 0, 0, 0);
    }
    float bb = b1[n];
    #pragma unroll
    for (int r = 0; r < 4; r++) {
        float y = fmaxf(acc[r] + bb, 0.0f);
        unsigned short hi, lo; splitf(y, hi, lo);
        y1H_g[(size_t)(m0 + quad * 4 + r) * 512 + n] = hi;
        y1L_g[(size_t)(m0 + quad * 4 + r) * 512 + n] = lo;
    }
}

// ---------------- K6: MLP2 out = hnF + y1@W2+b2 — grid (4,16) = 64 blocks,
// 4 waves, 1 16x16 tile/wave.
__global__ __launch_bounds__(256) void k_mlp2(
    const unsigned short* __restrict__ y1H_g, const unsigned short* __restrict__ y1L_g,
    const unsigned short* __restrict__ W2Th, const unsigned short* __restrict__ W2Tl,
    const float* __restrict__ b2, const float* __restrict__ hnF,
    float* __restrict__ out)
{
    int ncl = blockIdx.x, mtile = blockIdx.y, t = threadIdx.x;
    int m0 = mtile * 16;
    __shared__ __align__(16) unsigned short yH[16][520];
    __shared__ __align__(16) unsigned short yL[16][520];
    {
        int r = t >> 4, c0 = (t & 15) * 32;
        #pragma unroll
        for (int i = 0; i < 4; i++) {
            *(v8s*)&yH[r][c0 + i * 8] = *(const v8s*)&y1H_g[(size_t)(m0 + r) * 512 + c0 + i * 8];
            *(v8s*)&yL[r][c0 + i * 8] = *(const v8s*)&y1L_g[(size_t)(m0 + r) * 512 + c0 + i * 8];
        }
    }
    __syncthreads();

    int w = t >> 6, lane = t & 63, quad = lane >> 4, l16 = lane & 15;
    int n = (ncl * 4 + w) * 16 + l16;       // 0..255
    v4f acc = (v4f){0.f, 0.f, 0.f, 0.f};
    #pragma unroll
    for (int kk = 0; kk < 16; kk++) {
        int ko = kk * 32 + quad * 8;
        v8s ah = *(const v8s*)&yH[l16][ko];
        v8s al = *(const v8s*)&yL[l16][ko];
        v8s bh = *(const v8s*)&W2Th[(size_t)n * 512 + ko];
        v8s bl = *(const v8s*)&W2Tl[(size_t)n * 512 + ko];
        acc = __builtin_amdgcn_mfma_f32_16x16x32_bf16(al, bh, acc, 0, 0, 0);
        acc = __builtin_amdgcn_mfma_f32_16x16x32_bf16(ah, bl, acc, 0, 0, 0);
        acc = __builtin_amdgcn_mfma_f32_16x16x32_bf16(ah, bh, acc, 0, 0, 0);
    }
    float bb = b2[n];
    #pragma unroll
    for (int r = 0; r < 4; r++) {
        int m = m0 + quad * 4 + r;
        out[(size_t)m * 256 + n] = hnF[(size_t)m * 256 + n] + acc[r] + bb;
    }
}

extern "C" void kernel_launch(void* const* d_in, const int* in_sizes, int n_in,
                              void* d_out, int out_size, void* d_ws, size_t ws_size,
                              hipStream_t stream) {
    const float* features = (const float*)d_in[0];
    const float* slots    = (const float*)d_in[1];
    const float* Wq   = (const float*)d_in[2];
    const float* bq   = (const float*)d_in[3];
    const float* Wk   = (const float*)d_in[4];
    const float* bk   = (const float*)d_in[5];
    const float* Wv   = (const float*)d_in[6];
    const float* bv   = (const float*)d_in[7];
    const float* W_ih = (const float*)d_in[8];
    const float* b_ih = (const float*)d_in[9];
    const float* W_hh = (const float*)d_in[10];
    const float* b_hh = (const float*)d_in[11];
    const float* g_pre  = (const float*)d_in[12];
    const float* b_pre  = (const float*)d_in[13];
    const float* g_post = (const float*)d_in[14];
    const float* b_post = (const float*)d_in[15];
    const float* W1 = (const float*)d_in[16];
    const float* b1 = (const float*)d_in[17];
    const float* W2 = (const float*)d_in[18];
    const float* b2 = (const float*)d_in[19];
    float* out = (float*)d_out;

    // ws layout (~4.6 MB):
    //   G f32 1.5MB (aliases qkT 256KB + qb; G dead after k_gru)
    //   W1T/W2T hi/lo 4x256KB  (live until k_mlp2)
    //   Wih/Whh hi/lo 4x384KB  (dead after k_gate; ln + y1 alias here)
    //   WvT hi/lo 2x64KB       (dead after k_attn)
    //   hnF 256KB
    char* wsb = (char*)d_ws;
    float* G               = (float*)wsb;
    unsigned short* qkT_ws = (unsigned short*)wsb;
    float* qb_ws           = (float*)(wsb + 262144);
    unsigned short* W1Th   = (unsigned short*)(wsb + 1572864);
    unsigned short* W1Tl   = (unsigned short*)(wsb + 1835008);
    unsigned short* W2Th   = (unsigned short*)(wsb + 2097152);
    unsigned short* W2Tl   = (unsigned short*)(wsb + 2359296);
    unsigned short* WihH   = (unsigned short*)(wsb + 2621440);
    unsigned short* WihL   = (unsigned short*)(wsb + 3014656);
    unsigned short* WhhH   = (unsigned short*)(wsb + 3407872);
    unsigned short* WhhL   = (unsigned short*)(wsb + 3801088);
    unsigned short* WvTH   = (unsigned short*)(wsb + 4194304);
    unsigned short* WvTl   = (unsigned short*)(wsb + 4259840);
    float* hnF             = (float*)(wsb + 4325376);
    // tail intermediates alias the dead Wih/Whh region (2621440..4194304):
    unsigned short* lnH_g  = (unsigned short*)(wsb + 2621440);   // 128KB
    unsigned short* lnL_g  = (unsigned short*)(wsb + 2752512);   // 128KB
    unsigned short* y1H_g  = (unsigned short*)(wsb + 2883584);   // 256KB
    unsigned short* y1L_g  = (unsigned short*)(wsb + 3145728);   // 256KB (ends 3407872)
    float* agg_ws = out;   // agg accumulator in d_out (zeroed by K1)

    k_prep<<<dim3(592), dim3(256), 0, stream>>>(
        slots, Wq, bq, g_pre, b_pre, Wk, bk, W1, W2, W_ih, W_hh, Wv,
        qkT_ws, qb_ws, W1Th, W1Tl, W2Th, W2Tl,
        WihH, WihL, WhhH, WhhL, WvTH, WvTl, agg_ws);
    k_attn<<<dim3(16, 32), dim3(256), 0, stream>>>(
        features, WvTH, WvTl, bv, qkT_ws, qb_ws, agg_ws);
    k_gate<<<dim3(24, 16), dim3(256), 0, stream>>>(
        agg_ws, slots, WihH, WihL, b_ih, WhhH, WhhL, b_hh, G);
    k_gru<<<dim3(64), dim3(256), 0, stream>>>(
        slots, G, g_post, b_post, lnH_g, lnL_g, hnF);
    k_mlp1<<<dim3(8, 16), dim3(256), 0, stream>>>(
        lnH_g, lnL_g, W1Th, W1Tl, b1, y1H_g, y1L_g);
    k_mlp2<<<dim3(4, 16), dim3(256), 0, stream>>>(
        y1H_g, y1L_g, W2Th, W2Tl, b2, hnF, out);
}

// Round 9
// 176.374 us; speedup vs baseline: 1.0212x; 1.0212x over previous
//
#include <hip/hip_runtime.h>
#include <hip/hip_bf16.h>

#define NSLOT 8
#define SDIM 256
#define FDIM 128
#define NHEAD 4
#define HDIM 64
#define NPOS 4096

typedef short v8s __attribute__((ext_vector_type(8)));
typedef short v4s __attribute__((ext_vector_type(4)));
typedef float v4f __attribute__((ext_vector_type(4)));

__device__ __forceinline__ unsigned short f2bf(float x) {
    __hip_bfloat16 h = __float2bfloat16(x);
    unsigned short u; __builtin_memcpy(&u, &h, 2); return u;
}
__device__ __forceinline__ float bfr2f(unsigned short u) {
    __hip_bfloat16 h; __builtin_memcpy(&h, &u, 2); return __bfloat162float(h);
}
__device__ __forceinline__ void splitf(float x, unsigned short& hi, unsigned short& lo) {
    hi = f2bf(x);
    lo = f2bf(x - bfr2f(hi));
}

// ---------------- K1 (fused prep, 592 blocks):
//   blk   0..255: per-(batch,slot) LN+q+qkT/qb (b = blk>>3, s = blk&7)
//   blk 256..511: W1 / W2 transpose -> hi/lo bf16 [n][k]
//   blk 512..559: W_ih / W_hh (768x256 each) elementwise split -> hi/lo bf16
//   blk 560..591: Wv (128x256) transpose -> WvT hi/lo bf16 [256][128]
__global__ __launch_bounds__(256) void k_prep(
    const float* __restrict__ slots,
    const float* __restrict__ Wq, const float* __restrict__ bq,
    const float* __restrict__ g_pre, const float* __restrict__ b_pre,
    const float* __restrict__ Wk, const float* __restrict__ bk,
    const float* __restrict__ W1, const float* __restrict__ W2,
    const float* __restrict__ W_ih, const float* __restrict__ W_hh,
    const float* __restrict__ Wv,
    unsigned short* __restrict__ qkT_ws, float* __restrict__ qb_ws,
    unsigned short* __restrict__ W1Th, unsigned short* __restrict__ W1Tl,
    unsigned short* __restrict__ W2Th, unsigned short* __restrict__ W2Tl,
    unsigned short* __restrict__ WihH, unsigned short* __restrict__ WihL,
    unsigned short* __restrict__ WhhH, unsigned short* __restrict__ WhhL,
    unsigned short* __restrict__ WvTH, unsigned short* __restrict__ WvTl,
    float* __restrict__ agg_ws)
{
    int blk = blockIdx.x, t = threadIdx.x;
    __shared__ __align__(16) float s_ln[256];
    __shared__ __align__(16) float q_l[256];
    __shared__ float r1[4], r2[4];
    __shared__ float tl[32][33];

    if (blk >= 560) {                // WvT transpose+split (32 blocks)
        int id3 = blk - 560;
        int k0 = (id3 & 3) * 32, n0 = (id3 >> 2) * 32;
        for (int i = 0; i < 4; i++) {
            int idx = i * 256 + t, r = idx >> 5, c = idx & 31;
            tl[r][c] = Wv[(size_t)(k0 + r) * 256 + n0 + c];
        }
        __syncthreads();
        for (int i = 0; i < 4; i++) {
            int idx = i * 256 + t, r = idx >> 5, c = idx & 31;
            unsigned short hi, lo; splitf(tl[c][r], hi, lo);
            WvTH[(size_t)(n0 + r) * 128 + k0 + c] = hi;
            WvTl[(size_t)(n0 + r) * 128 + k0 + c] = lo;
        }
        return;
    }
    if (blk >= 512) {                // gate-weight split: 768 rows each (24 blocks each)
        int id2 = blk - 512;         // 0..47
        const float* src; unsigned short *dh, *dl; int r0;
        if (id2 < 24) { src = W_ih; dh = WihH; dl = WihL; r0 = id2 * 32; }
        else          { src = W_hh; dh = WhhH; dl = WhhL; r0 = (id2 - 24) * 32; }
        for (int i = 0; i < 32; i++) {
            size_t idx = (size_t)(r0 + i) * 256 + t;
            unsigned short hi, lo; splitf(src[idx], hi, lo);
            dh[idx] = hi; dl[idx] = lo;
        }
        return;
    }
    if (blk >= 256) {                // W1/W2 transpose+split
        int id = blk - 256;          // 0..255
        const float* src; unsigned short *dh, *dl; int N, K, k0, n0;
        if (id < 128) { src = W1; dh = W1Th; dl = W1Tl; N = 512; K = 256;
                        k0 = (id >> 4) * 32; n0 = (id & 15) * 32; }
        else          { int i2 = id - 128; src = W2; dh = W2Th; dl = W2Tl; N = 256; K = 512;
                        k0 = (i2 >> 3) * 32; n0 = (i2 & 7) * 32; }
        for (int i = 0; i < 4; i++) {
            int idx = i * 256 + t, r = idx >> 5, c = idx & 31;
            tl[r][c] = src[(size_t)(k0 + r) * N + n0 + c];
        }
        __syncthreads();
        for (int i = 0; i < 4; i++) {
            int idx = i * 256 + t, r = idx >> 5, c = idx & 31;
            unsigned short hi, lo; splitf(tl[c][r], hi, lo);
            dh[(size_t)(n0 + r) * K + k0 + c] = hi;
            dl[(size_t)(n0 + r) * K + k0 + c] = lo;
        }
        return;
    }

    // ---- per-(batch,slot) prep: b = blk>>3, s = blk&7 ----
    int b = blk >> 3, s = blk & 7;
    if (s == 0)
        for (int i = 0; i < 8; i++) agg_ws[b * 2048 + i * 256 + t] = 0.0f;

    // LN of slot row (b,s): one element per thread
    float x = slots[(size_t)(b * 8 + s) * 256 + t];
    float sum = x, sq = x * x;
    #pragma unroll
    for (int m = 1; m <= 32; m <<= 1) {
        sum += __shfl_xor(sum, m, 64);
        sq  += __shfl_xor(sq, m, 64);
    }
    int w = t >> 6, lane = t & 63;
    if (lane == 0) { r1[w] = sum; r2[w] = sq; }
    __syncthreads();
    sum = r1[0] + r1[1] + r1[2] + r1[3];
    sq  = r2[0] + r2[1] + r2[2] + r2[3];
    float mu  = sum * (1.0f / 256);
    float var = sq * (1.0f / 256) - mu * mu;
    float rstd = rsqrtf(var + 1e-5f);
    s_ln[t] = (x - mu) * rstd * g_pre[t] + b_pre[t];
    __syncthreads();

    // q column t for this slot: q[t] = bq[t] + sum_k ln[k]*Wq[k][t]
    float qacc = bq[t];
    for (int k = 0; k < 256; k += 4) {
        float4 l4 = *(const float4*)&s_ln[k];       // uniform -> LDS broadcast
        qacc += l4.x * Wq[(k + 0) * 256 + t]
              + l4.y * Wq[(k + 1) * 256 + t]
              + l4.z * Wq[(k + 2) * 256 + t]
              + l4.w * Wq[(k + 3) * 256 + t];
    }
    q_l[t] = qacc;
    __syncthreads();

    // qkT rows (h*8+s) for this slot: thread (c = t&127) does heads h0, h0+2
    int c = t & 127, h0 = t >> 7;
    #pragma unroll
    for (int hi_ = 0; hi_ < 2; hi_++) {
        int hh = h0 + hi_ * 2;
        const float4* wk4 = (const float4*)&Wk[(size_t)c * 256 + hh * 64];
        const float4* q4  = (const float4*)&q_l[hh * 64];
        float acc = 0.0f;
        #pragma unroll
        for (int d4 = 0; d4 < 16; d4++) {
            float4 wv = wk4[d4]; float4 qv = q4[d4];
            acc += wv.x * qv.x + wv.y * qv.y + wv.z * qv.z + wv.w * qv.w;
        }
        qkT_ws[(size_t)(b * 32 + hh * 8 + s) * 128 + c] = f2bf(acc);
    }
    if (t < 4) {
        float acc = 0.0f;
        for (int d = 0; d < 64; d++)
            acc += bk[t * 64 + d] * q_l[t * 64 + d];
        qb_ws[b * 32 + t * 8 + s] = acc;
    }
}

// ---------------- K2: MFMA scores + in-register softmax + MFMA attF^T + epi.
// Grid (16,32). NEW: 2-deep register prefetch (fva/fvb) — tiles tt+1 AND
// tt+2 in flight, covering ~2 tt bodies (~1000 cyc) of HBM latency (~900
// cyc, m126) so the stage at top of each tt no longer stalls on vmcnt.
__global__ __launch_bounds__(256, 4) void k_attn(
    const float* __restrict__ feat,   // (B,128,4096)
    const unsigned short* __restrict__ WvTH, const unsigned short* __restrict__ WvTl,
    const float* __restrict__ bv,
    const unsigned short* __restrict__ qkT, const float* __restrict__ qb_ws,
    float* __restrict__ agg_ws)
{
    __shared__ __align__(16) char smem[26752];
    unsigned short* featPC = (unsigned short*)smem;              // stride 136
    unsigned short* featCP = (unsigned short*)(smem + 8704);     // stride 56
    unsigned short* attFH  = (unsigned short*)smem;              // alias, stride 136
    unsigned short* attFL  = (unsigned short*)(smem + 8704);     // alias, stride 136
    unsigned short* s_aT   = (unsigned short*)(smem + 23040);    // stride 56
    float*          s_S    = (float*)(smem + 26624);

    int t = threadIdx.x, b = blockIdx.y, n0 = blockIdx.x * 256;
    int wv_ = t >> 6, lane = t & 63, quad = lane >> 4, l16 = lane & 15;
    int mt = wv_ >> 1, nt = wv_ & 1;
    int sp  = l16 + mt * 16;
    int shs = l16 + nt * 16;

    v8s bq_[4];
    #pragma unroll
    for (int ch = 0; ch < 4; ch++)
        bq_[ch] = *(const v8s*)&qkT[(b * 32 + shs) * 128 + ch * 32 + quad * 8];
    float qbv = qb_ws[b * 32 + shs];
    if (t < 32) s_S[t] = 0.0f;

    v4f accF[4];
    #pragma unroll
    for (int i = 0; i < 4; i++) accF[i] = (v4f){0.f, 0.f, 0.f, 0.f};
    float sS_reg = 0.0f;

    int c0 = (t >> 3) * 4, p0 = (t & 7) * 4;
    size_t fbase = (size_t)b * (FDIM * NPOS);

    // 2-deep prefetch: tiles 0 and 1 issued before the loop
    float fva[4][4], fvb[4][4];
    #pragma unroll
    for (int r = 0; r < 4; r++) {
        float4 f = *(const float4*)&feat[fbase + (size_t)(c0 + r) * NPOS + n0 + p0];
        fva[r][0] = f.x; fva[r][1] = f.y; fva[r][2] = f.z; fva[r][3] = f.w;
    }
    #pragma unroll
    for (int r = 0; r < 4; r++) {
        float4 f = *(const float4*)&feat[fbase + (size_t)(c0 + r) * NPOS + n0 + 32 + p0];
        fvb[r][0] = f.x; fvb[r][1] = f.y; fvb[r][2] = f.z; fvb[r][3] = f.w;
    }

    #pragma unroll
    for (int tt = 0; tt < 8; ++tt) {
        // compile-time buffer select (loop fully unrolled -> no scratch)
        float (*fv)[4] = (tt & 1) ? fvb : fva;
        __syncthreads();
        // stage: convert ONCE, write both layouts
        unsigned short us[4][4];
        #pragma unroll
        for (int r = 0; r < 4; r++)
            #pragma unroll
            for (int j = 0; j < 4; j++) us[r][j] = f2bf(fv[r][j]);
        #pragma unroll
        for (int r = 0; r < 4; r++)
            *(v4s*)&featCP[(c0 + r) * 56 + p0] =
                (v4s){(short)us[r][0], (short)us[r][1], (short)us[r][2], (short)us[r][3]};
        #pragma unroll
        for (int j = 0; j < 4; j++)
            *(v4s*)&featPC[(p0 + j) * 136 + c0] =
                (v4s){(short)us[0][j], (short)us[1][j], (short)us[2][j], (short)us[3][j]};
        __syncthreads();

        // refill the just-consumed buffer with tile tt+2 (T14, depth 2)
        if (tt < 6) {
            #pragma unroll
            for (int r = 0; r < 4; r++) {
                float4 f = *(const float4*)&feat[fbase + (size_t)(c0 + r) * NPOS
                                                 + n0 + (tt + 2) * 32 + p0];
                fv[r][0] = f.x; fv[r][1] = f.y; fv[r][2] = f.z; fv[r][3] = f.w;
            }
        }

        v4f acc = (v4f){0.f, 0.f, 0.f, 0.f};
        #pragma unroll
        for (int ch = 0; ch < 4; ch++) {
            v8s a = *(const v8s*)&featPC[sp * 136 + ch * 32 + quad * 8];
            acc = __builtin_amdgcn_mfma_f32_16x16x32_bf16(a, bq_[ch], acc, 0, 0, 0);
        }

        // ---- in-register softmax over the 8-lane slot group ----
        float p[4];
        {
            float sc[4], e[4];
            #pragma unroll
            for (int r = 0; r < 4; r++) sc[r] = (acc[r] + qbv) * 0.125f;
            #pragma unroll
            for (int r = 0; r < 4; r++) {
                float m = sc[r];
                m = fmaxf(m, __shfl_xor(m, 1, 64));
                m = fmaxf(m, __shfl_xor(m, 2, 64));
                m = fmaxf(m, __shfl_xor(m, 4, 64));
                e[r] = __expf(sc[r] - m);
            }
            #pragma unroll
            for (int r = 0; r < 4; r++) {
                float ssum = e[r];
                ssum += __shfl_xor(ssum, 1, 64);
                ssum += __shfl_xor(ssum, 2, 64);
                ssum += __shfl_xor(ssum, 4, 64);
                p[r] = e[r] * (1.0f / ssum);
            }
        }
        // write P in [col][pos] layout for the PV MFMA A-operand
        *(v4s*)&s_aT[shs * 56 + mt * 16 + quad * 4] =
            (v4s){(short)f2bf(p[0]), (short)f2bf(p[1]),
                  (short)f2bf(p[2]), (short)f2bf(p[3])};
        // accumulate column sum (this wave's 16 positions) in a register
        {
            float sl = p[0] + p[1] + p[2] + p[3];
            sl += __shfl_xor(sl, 16, 64);
            sl += __shfl_xor(sl, 32, 64);
            sS_reg += sl;
        }
        __syncthreads();

        v8s aA0 = *(const v8s*)&s_aT[l16 * 56 + quad * 8];
        v8s aA1 = *(const v8s*)&s_aT[(l16 + 16) * 56 + quad * 8];
        v8s bF0 = *(const v8s*)&featCP[(l16 + wv_ * 32) * 56 + quad * 8];
        v8s bF1 = *(const v8s*)&featCP[(l16 + wv_ * 32 + 16) * 56 + quad * 8];
        accF[0] = __builtin_amdgcn_mfma_f32_16x16x32_bf16(aA0, bF0, accF[0], 0, 0, 0);
        accF[1] = __builtin_amdgcn_mfma_f32_16x16x32_bf16(aA0, bF1, accF[1], 0, 0, 0);
        accF[2] = __builtin_amdgcn_mfma_f32_16x16x32_bf16(aA1, bF0, accF[2], 0, 0, 0);
        accF[3] = __builtin_amdgcn_mfma_f32_16x16x32_bf16(aA1, bF1, accF[3], 0, 0, 0);
    }
    // flush the per-wave column sums
    if (quad == 0) atomicAdd(&s_S[shs], sS_reg);
    __syncthreads();                 // feats views dead; alias as attFH/attFL
    #pragma unroll
    for (int mt2 = 0; mt2 < 2; mt2++)
        #pragma unroll
        for (int ntl = 0; ntl < 2; ntl++) {
            v4f f = accF[mt2 * 2 + ntl];
            int cc = wv_ * 32 + ntl * 16 + l16;
            #pragma unroll
            for (int r = 0; r < 4; r++) {
                unsigned short hi, lo; splitf(f[r], hi, lo);
                attFH[(mt2 * 16 + quad * 4 + r) * 136 + cc] = hi;
                attFL[(mt2 * 16 + quad * 4 + r) * 136 + cc] = lo;
            }
        }
    __syncthreads();

    int h = wv_;
    int am = h * 8 + (l16 & 7);
    for (int nt2 = 0; nt2 < 4; nt2++) {
        int n = h * 64 + nt2 * 16 + l16;
        v4f acc = (v4f){0.f, 0.f, 0.f, 0.f};
        #pragma unroll
        for (int kk = 0; kk < 4; kk++) {
            int ko = kk * 32 + quad * 8;
            v8s ah = *(const v8s*)&attFH[am * 136 + ko];
            v8s al = *(const v8s*)&attFL[am * 136 + ko];
            v8s bh = *(const v8s*)&WvTH[(size_t)n * 128 + ko];
            v8s bl = *(const v8s*)&WvTl[(size_t)n * 128 + ko];
            acc = __builtin_amdgcn_mfma_f32_16x16x32_bf16(al, bh, acc, 0, 0, 0);
            acc = __builtin_amdgcn_mfma_f32_16x16x32_bf16(ah, bl, acc, 0, 0, 0);
            acc = __builtin_amdgcn_mfma_f32_16x16x32_bf16(ah, bh, acc, 0, 0, 0);
        }
        float bvn = bv[n];
        if (quad < 2) {
            #pragma unroll
            for (int r = 0; r < 4; r++) {
                int s = quad * 4 + r;
                atomicAdd(&agg_ws[b * 2048 + s * 256 + n],
                          acc[r] + s_S[h * 8 + s] * bvn);
            }
        }
    }
}

// ---------------- K3: G[256][1536] = [x@W_ih^T + b_ih | h@W_hh^T + b_hh] ---
// 384 blocks (24 ntiles x 16 mtiles), 4 waves, ONE 16x16 tile per wave.
__global__ __launch_bounds__(256) void k_gate(
    const float* __restrict__ agg, const float* __restrict__ slots,
    const unsigned short* __restrict__ WihH, const unsigned short* __restrict__ WihL,
    const float* __restrict__ b_ih,
    const unsigned short* __restrict__ WhhH, const unsigned short* __restrict__ WhhL,
    const float* __restrict__ b_hh,
    float* __restrict__ G)
{
    int ntile = blockIdx.x, mtile = blockIdx.y, t = threadIdx.x;
    bool hhalf = ntile >= 12;
    int jbase = (hhalf ? ntile - 12 : ntile) * 64;
    const float* X = hhalf ? slots : agg;
    const unsigned short* BH = hhalf ? WhhH : WihH;
    const unsigned short* BL = hhalf ? WhhL : WihL;
    const float* bias = hhalf ? b_hh : b_ih;
    int gofs = hhalf ? 768 : 0;
    int m0 = mtile * 16;

    __shared__ __align__(16) unsigned short aH[16][264];
    __shared__ __align__(16) unsigned short aL[16][264];
    for (int i = 0; i < 4; i++) {
        int idx = i * 256 + t;           // 0..1023
        int r = idx >> 6, q = idx & 63;
        float4 f = *(const float4*)&X[(size_t)(m0 + r) * 256 + q * 4];
        unsigned short h0,l0,h1,l1,h2,l2,h3,l3;
        splitf(f.x, h0, l0); splitf(f.y, h1, l1);
        splitf(f.z, h2, l2); splitf(f.w, h3, l3);
        *(v4s*)&aH[r][q * 4] = (v4s){(short)h0,(short)h1,(short)h2,(short)h3};
        *(v4s*)&aL[r][q * 4] = (v4s){(short)l0,(short)l1,(short)l2,(short)l3};
    }
    __syncthreads();

    int w = t >> 6, lane = t & 63, quad = lane >> 4, l16 = lane & 15;
    int jrow = jbase + w * 16 + l16;     // 0..767
    v4f acc = (v4f){0.f, 0.f, 0.f, 0.f};
    #pragma unroll
    for (int kk = 0; kk < 8; kk++) {
        int ko = kk * 32 + quad * 8;
        v8s ah = *(const v8s*)&aH[l16][ko];
        v8s al = *(const v8s*)&aL[l16][ko];
        v8s bh = *(const v8s*)&BH[(size_t)jrow * 256 + ko];
        v8s bl = *(const v8s*)&BL[(size_t)jrow * 256 + ko];
        acc = __builtin_amdgcn_mfma_f32_16x16x32_bf16(al, bh, acc, 0, 0, 0);
        acc = __builtin_amdgcn_mfma_f32_16x16x32_bf16(ah, bl, acc, 0, 0, 0);
        acc = __builtin_amdgcn_mfma_f32_16x16x32_bf16(ah, bh, acc, 0, 0, 0);
    }
    float bv_ = bias[jrow];
    int gj = gofs + jbase + w * 16 + l16;
    #pragma unroll
    for (int r = 0; r < 4; r++)
        G[(size_t)(m0 + quad * 4 + r) * 1536 + gj] = acc[r] + bv_;
}

__device__ __forceinline__ float gru1(float ir, float iz, float in_,
                                      float hr, float hz, float hn, float hp) {
    float r = 1.0f / (1.0f + __expf(-(ir + hr)));
    float z = 1.0f / (1.0f + __expf(-(iz + hz)));
    float n = tanhf(in_ + r * hn);
    return (1.0f - z) * n + z * hp;
}

// ---------------- K4: GRU + post-LN, 64 blocks x 256 thr, 4 rows/block.
__global__ __launch_bounds__(256) void k_gru(
    const float* __restrict__ slots, const float* __restrict__ G,
    const float* __restrict__ g_post, const float* __restrict__ b_post,
    unsigned short* __restrict__ lnH_g, unsigned short* __restrict__ lnL_g,
    float* __restrict__ hnF)
{
    __shared__ float pS[4][4], pQ[4][4];
    int t = threadIdx.x, m0 = blockIdx.x * 4;
    int w = t >> 6, lane = t & 63;

    float hnew[4];
    #pragma unroll
    for (int r = 0; r < 4; r++) {
        int row = m0 + r;
        const float* gp = &G[(size_t)row * 1536 + t];
        float hp = slots[(size_t)row * 256 + t];
        hnew[r] = gru1(gp[0], gp[256], gp[512], gp[768], gp[1024], gp[1280], hp);
        hnF[(size_t)row * 256 + t] = hnew[r];
    }
    float ps[4], pq[4];
    #pragma unroll
    for (int r = 0; r < 4; r++) { ps[r] = hnew[r]; pq[r] = hnew[r] * hnew[r]; }
    #pragma unroll
    for (int mm = 1; mm <= 32; mm <<= 1)
        #pragma unroll
        for (int r = 0; r < 4; r++) {
            ps[r] += __shfl_xor(ps[r], mm, 64);
            pq[r] += __shfl_xor(pq[r], mm, 64);
        }
    if (lane == 0)
        #pragma unroll
        for (int r = 0; r < 4; r++) { pS[r][w] = ps[r]; pQ[r][w] = pq[r]; }
    __syncthreads();
    float gpv = g_post[t], bpv = b_post[t];
    #pragma unroll
    for (int r = 0; r < 4; r++) {
        float s = pS[r][0] + pS[r][1] + pS[r][2] + pS[r][3];
        float q = pQ[r][0] + pQ[r][1] + pQ[r][2] + pQ[r][3];
        float mu = s * (1.0f / 256);
        float var = q * (1.0f / 256) - mu * mu;
        float rstd = rsqrtf(var + 1e-5f);
        float ln = (hnew[r] - mu) * rstd * gpv + bpv;
        unsigned short hi, lo; splitf(ln, hi, lo);
        lnH_g[(size_t)(m0 + r) * 256 + t] = hi;
        lnL_g[(size_t)(m0 + r) * 256 + t] = lo;
    }
}

// ---------------- K5: MLP1 y1 = relu(ln@W1+b1) — grid (8,16) = 128 blocks,
// 4 waves, 1 16x16 tile/wave.
__global__ __launch_bounds__(256) void k_mlp1(
    const unsigned short* __restrict__ lnH_g, const unsigned short* __restrict__ lnL_g,
    const unsigned short* __restrict__ W1Th, const unsigned short* __restrict__ W1Tl,
    const float* __restrict__ b1,
    unsigned short* __restrict__ y1H_g, unsigned short* __restrict__ y1L_g)
{
    int ncl = blockIdx.x, mtile = blockIdx.y, t = threadIdx.x;
    int m0 = mtile * 16;
    __shared__ __align__(16) unsigned short aH[16][264];
    __shared__ __align__(16) unsigned short aL[16][264];
    {
        int r = t >> 4, c0 = (t & 15) * 16;
        *(v8s*)&aH[r][c0]     = *(const v8s*)&lnH_g[(size_t)(m0 + r) * 256 + c0];
        *(v8s*)&aH[r][c0 + 8] = *(const v8s*)&lnH_g[(size_t)(m0 + r) * 256 + c0 + 8];
        *(v8s*)&aL[r][c0]     = *(const v8s*)&lnL_g[(size_t)(m0 + r) * 256 + c0];
        *(v8s*)&aL[r][c0 + 8] = *(const v8s*)&lnL_g[(size_t)(m0 + r) * 256 + c0 + 8];
    }
    __syncthreads();

    int w = t >> 6, lane = t & 63, quad = lane >> 4, l16 = lane & 15;
    int n = (ncl * 4 + w) * 16 + l16;       // 0..511
    v4f acc = (v4f){0.f, 0.f, 0.f, 0.f};
    #pragma unroll
    for (int kk = 0; kk < 8; kk++) {
        int ko = kk * 32 + quad * 8;
        v8s ah = *(const v8s*)&aH[l16][ko];
        v8s al = *(const v8s*)&aL[l16][ko];
        v8s bh = *(const v8s*)&W1Th[(size_t)n * 256 + ko];
        v8s bl = *(const v8s*)&W1Tl[(size_t)n * 256 + ko];
        acc = __builtin_amdgcn_mfma_f32_16x16x32_bf16(al, bh, acc, 0, 0, 0);
        acc = __builtin_amdgcn_mfma_f32_16x16x32_bf16(ah, bl, acc, 0, 0, 0);
        acc = __builtin_amdgcn_mfma_f32_16x16x32_bf16(ah, bh, acc, 0, 0, 0);
    }
    float bb = b1[n];
    #pragma unroll
    for (int r = 0; r < 4; r++) {
        float y = fmaxf(acc[r] + bb, 0.0f);
        unsigned short hi, lo; splitf(y, hi, lo);
        y1H_g[(size_t)(m0 + quad * 4 + r) * 512 + n] = hi;
        y1L_g[(size_t)(m0 + quad * 4 + r) * 512 + n] = lo;
    }
}

// ---------------- K6: MLP2 out = hnF + y1@W2+b2 — grid (4,16) = 64 blocks,
// 4 waves, 1 16x16 tile/wave.
__global__ __launch_bounds__(256) void k_mlp2(
    const unsigned short* __restrict__ y1H_g, const unsigned short* __restrict__ y1L_g,
    const unsigned short* __restrict__ W2Th, const unsigned short* __restrict__ W2Tl,
    const float* __restrict__ b2, const float* __restrict__ hnF,
    float* __restrict__ out)
{
    int ncl = blockIdx.x, mtile = blockIdx.y, t = threadIdx.x;
    int m0 = mtile * 16;
    __shared__ __align__(16) unsigned short yH[16][520];
    __shared__ __align__(16) unsigned short yL[16][520];
    {
        int r = t >> 4, c0 = (t & 15) * 32;
        #pragma unroll
        for (int i = 0; i < 4; i++) {
            *(v8s*)&yH[r][c0 + i * 8] = *(const v8s*)&y1H_g[(size_t)(m0 + r) * 512 + c0 + i * 8];
            *(v8s*)&yL[r][c0 + i * 8] = *(const v8s*)&y1L_g[(size_t)(m0 + r) * 512 + c0 + i * 8];
        }
    }
    __syncthreads();

    int w = t >> 6, lane = t & 63, quad = lane >> 4, l16 = lane & 15;
    int n = (ncl * 4 + w) * 16 + l16;       // 0..255
    v4f acc = (v4f){0.f, 0.f, 0.f, 0.f};
    #pragma unroll
    for (int kk = 0; kk < 16; kk++) {
        int ko = kk * 32 + quad * 8;
        v8s ah = *(const v8s*)&yH[l16][ko];
        v8s al = *(const v8s*)&yL[l16][ko];
        v8s bh = *(const v8s*)&W2Th[(size_t)n * 512 + ko];
        v8s bl = *(const v8s*)&W2Tl[(size_t)n * 512 + ko];
        acc = __builtin_amdgcn_mfma_f32_16x16x32_bf16(al, bh, acc, 0, 0, 0);
        acc = __builtin_amdgcn_mfma_f32_16x16x32_bf16(ah, bl, acc, 0, 0, 0);
        acc = __builtin_amdgcn_mfma_f32_16x16x32_bf16(ah, bh, acc, 0, 0, 0);
    }
    float bb = b2[n];
    #pragma unroll
    for (int r = 0; r < 4; r++) {
        int m = m0 + quad * 4 + r;
        out[(size_t)m * 256 + n] = hnF[(size_t)m * 256 + n] + acc[r] + bb;
    }
}

extern "C" void kernel_launch(void* const* d_in, const int* in_sizes, int n_in,
                              void* d_out, int out_size, void* d_ws, size_t ws_size,
                              hipStream_t stream) {
    const float* features = (const float*)d_in[0];
    const float* slots    = (const float*)d_in[1];
    const float* Wq   = (const float*)d_in[2];
    const float* bq   = (const float*)d_in[3];
    const float* Wk   = (const float*)d_in[4];
    const float* bk   = (const float*)d_in[5];
    const float* Wv   = (const float*)d_in[6];
    const float* bv   = (const float*)d_in[7];
    const float* W_ih = (const float*)d_in[8];
    const float* b_ih = (const float*)d_in[9];
    const float* W_hh = (const float*)d_in[10];
    const float* b_hh = (const float*)d_in[11];
    const float* g_pre  = (const float*)d_in[12];
    const float* b_pre  = (const float*)d_in[13];
    const float* g_post = (const float*)d_in[14];
    const float* b_post = (const float*)d_in[15];
    const float* W1 = (const float*)d_in[16];
    const float* b1 = (const float*)d_in[17];
    const float* W2 = (const float*)d_in[18];
    const float* b2 = (const float*)d_in[19];
    float* out = (float*)d_out;

    // ws layout (~4.6 MB):
    //   G f32 1.5MB (aliases qkT 256KB + qb; G dead after k_gru)
    //   W1T/W2T hi/lo 4x256KB  (live until k_mlp2)
    //   Wih/Whh hi/lo 4x384KB  (dead after k_gate; ln + y1 alias here)
    //   WvT hi/lo 2x64KB       (dead after k_attn)
    //   hnF 256KB
    char* wsb = (char*)d_ws;
    float* G               = (float*)wsb;
    unsigned short* qkT_ws = (unsigned short*)wsb;
    float* qb_ws           = (float*)(wsb + 262144);
    unsigned short* W1Th   = (unsigned short*)(wsb + 1572864);
    unsigned short* W1Tl   = (unsigned short*)(wsb + 1835008);
    unsigned short* W2Th   = (unsigned short*)(wsb + 2097152);
    unsigned short* W2Tl   = (unsigned short*)(wsb + 2359296);
    unsigned short* WihH   = (unsigned short*)(wsb + 2621440);
    unsigned short* WihL   = (unsigned short*)(wsb + 3014656);
    unsigned short* WhhH   = (unsigned short*)(wsb + 3407872);
    unsigned short* WhhL   = (unsigned short*)(wsb + 3801088);
    unsigned short* WvTH   = (unsigned short*)(wsb + 4194304);
    unsigned short* WvTl   = (unsigned short*)(wsb + 4259840);
    float* hnF             = (float*)(wsb + 4325376);
    // tail intermediates alias the dead Wih/Whh region (2621440..4194304):
    unsigned short* lnH_g  = (unsigned short*)(wsb + 2621440);   // 128KB
    unsigned short* lnL_g  = (unsigned short*)(wsb + 2752512);   // 128KB
    unsigned short* y1H_g  = (unsigned short*)(wsb + 2883584);   // 256KB
    unsigned short* y1L_g  = (unsigned short*)(wsb + 3145728);   // 256KB (ends 3407872)
    float* agg_ws = out;   // agg accumulator in d_out (zeroed by K1)

    k_prep<<<dim3(592), dim3(256), 0, stream>>>(
        slots, Wq, bq, g_pre, b_pre, Wk, bk, W1, W2, W_ih, W_hh, Wv,
        qkT_ws, qb_ws, W1Th, W1Tl, W2Th, W2Tl,
        WihH, WihL, WhhH, WhhL, WvTH, WvTl, agg_ws);
    k_attn<<<dim3(16, 32), dim3(256), 0, stream>>>(
        features, WvTH, WvTl, bv, qkT_ws, qb_ws, agg_ws);
    k_gate<<<dim3(24, 16), dim3(256), 0, stream>>>(
        agg_ws, slots, WihH, WihL, b_ih, WhhH, WhhL, b_hh, G);
    k_gru<<<dim3(64), dim3(256), 0, stream>>>(
        slots, G, g_post, b_post, lnH_g, lnL_g, hnF);
    k_mlp1<<<dim3(8, 16), dim3(256), 0, stream>>>(
        lnH_g, lnL_g, W1Th, W1Tl, b1, y1H_g, y1L_g);
    k_mlp2<<<dim3(4, 16), dim3(256), 0, stream>>>(
        y1H_g, y1L_g, W2Th, W2Tl, b2, hnF, out);
}